// Round 3
// baseline (170.745 us; speedup 1.0000x reference)
//
#include <hip/hip_runtime.h>
#include <hip/hip_bf16.h>
#include <cstdint>

#define N_SPK 1024
#define M_UTT 20
#define D_DIM 768
#define NM_ROWS (N_SPK * M_UTT)   // 20480 utterances / rows

static constexpr float EPS = 1e-8f;

// s_waitcnt immediates (gfx9): vmcnt[3:0]=bits3:0, expcnt=6:4, lgkmcnt=11:8,
// vmcnt[5:4]=bits15:14.
#define WAIT_VM0   0x0F70   // vmcnt=0,  lgkm/exp don't-wait
#define WAIT_VM24  0x4F78   // vmcnt=24 (hi=01,lo=8), lgkm/exp don't-wait
#define WAIT_LGKM0 0xC07F   // lgkmcnt=0, vmcnt/exp don't-wait

typedef __attribute__((ext_vector_type(4))) float floatx4;  // MFMA accumulator

__device__ __forceinline__ void load16_to_lds(const void* g, void* l) {
    __builtin_amdgcn_global_load_lds(
        (const __attribute__((address_space(1))) uint32_t*)g,
        (__attribute__((address_space(3))) uint32_t*)l, 16, 0, 0);
}

__device__ __forceinline__ float wave_sum(float v) {
    #pragma unroll
    for (int o = 32; o > 0; o >>= 1) v += __shfl_xor(v, o);
    return v;
}

// pack two f32 -> two OCP e4m3 bytes (low word of result)
__device__ __forceinline__ unsigned short fp8pk(float a, float b) {
    return (unsigned short)(__builtin_amdgcn_cvt_pk_fp8_f32(a, b, 0, false) & 0xFFFF);
}

// ---------------------------------------------------------------------------
// Kernel 1 (prep): per speaker, read emb once (float2/thread, 384 thr),
// centroid + 20 utterance norms; write FP8 e4m3 Ehat ([m][i][d]) and Chat.
// Zero-inits ctr/accum.  (unchanged — isolate the gemm change)
// ---------------------------------------------------------------------------
__global__ __launch_bounds__(384) void prep_kernel(const float* __restrict__ emb,
                                                   unsigned char* __restrict__ ehat,
                                                   unsigned char* __restrict__ chat,
                                                   int* __restrict__ ctr,
                                                   float* __restrict__ accum) {
    const int i = blockIdx.x;      // speaker
    const int t = threadIdx.x;     // 0..383
    const int wave = t >> 6, lane = t & 63;

    if (i == 0 && t == 0) { *ctr = 0; *accum = 0.f; }

    const float2* src = (const float2*)(emb + (size_t)i * M_UTT * D_DIM);

    float2 v[M_UTT];
    float ss[M_UTT];
    float2 cen = {0.f, 0.f};
    #pragma unroll
    for (int m = 0; m < M_UTT; ++m) {
        const float2 x = src[m * 384 + t];
        v[m] = x;
        ss[m] = x.x * x.x + x.y * x.y;
        cen.x += x.x; cen.y += x.y;
    }
    cen.x *= (1.f / M_UTT); cen.y *= (1.f / M_UTT);
    float css = cen.x * cen.x + cen.y * cen.y;

    __shared__ float red[M_UTT + 1][6];
    #pragma unroll
    for (int m = 0; m < M_UTT; ++m) {
        const float s = wave_sum(ss[m]);
        if (lane == 0) red[m][wave] = s;
    }
    {
        const float s = wave_sum(css);
        if (lane == 0) red[M_UTT][wave] = s;
    }
    __syncthreads();

    #pragma unroll
    for (int m = 0; m < M_UTT; ++m) {
        const float tot = red[m][0] + red[m][1] + red[m][2] +
                          red[m][3] + red[m][4] + red[m][5];
        const float rn = 1.0f / fmaxf(sqrtf(tot), EPS);
        ((unsigned short*)(ehat + ((size_t)(m * N_SPK + i)) * D_DIM))[t] =
            fp8pk(v[m].x * rn, v[m].y * rn);
    }
    {
        const float tot = red[M_UTT][0] + red[M_UTT][1] + red[M_UTT][2] +
                          red[M_UTT][3] + red[M_UTT][4] + red[M_UTT][5];
        const float rn = 1.0f / fmaxf(sqrtf(tot), EPS);
        ((unsigned short*)(chat + (size_t)i * D_DIM))[t] =
            fp8pk(cen.x * rn, cen.y * rn);
    }
}

// ---------------------------------------------------------------------------
// Kernel 2: FP8 single-wave GEMM, BK=128, 6 K-iterations.
// B evicted from LDS (direct global->VGPR, reg-dbuf via renaming);
// A keeps global_load_lds, dbuf 2x8KB -> LDS 16 KB total (10 blocks/CU cap,
// VGPR-capped ~8). Counted vmcnt(24) steady state (tile kt = oldest 8 A-lds +
// 16 B-reg loads); tile kt+2 issued after compute kt behind lgkmcnt(0).
// B bytes are identical to the old LDS path by construction:
//   boff[ks][jt] = (jt*16+c)*768 + (ks*2+(quad>>1))*16 + (quad&1)*8  (+kt*128)
// ---------------------------------------------------------------------------
__global__ __launch_bounds__(64) void gemm_fused_kernel(
        const unsigned char* __restrict__ ehat,
        const unsigned char* __restrict__ chat,
        const float* __restrict__ wp,
        float* __restrict__ Psum,
        float* __restrict__ T) {
    __shared__ unsigned char As[2][64 * 128];   // 2 x 8 KB (A only)

    const int lane = threadIdx.x;   // 0..63
    const int c = lane & 15;
    const int quad = lane >> 4;

    const int xcd = blockIdx.x & 7;
    const int idx = blockIdx.x >> 3;        // 0..639
    const int bu  = xcd * 40 + (idx >> 4);  // 0..319 (64-row tiles)
    const int bj  = idx & 15;               // 0..15  (bj fastest within XCD)
    const int m   = bu >> 4;                // 16 bu-tiles per m
    const int rb  = bu & 15;
    const int u0  = bu * 64;
    const int j0  = bj * 64;

    const unsigned char* Ag = ehat + (size_t)u0 * D_DIM;
    const unsigned char* Bg = chat + (size_t)j0 * D_DIM;

    // A staging geometry: 512 16B chunks; lane covers ci = s*64+lane
    int goff[8];
    #pragma unroll
    for (int s = 0; s < 8; ++s) {
        const int ci  = s * 64 + lane;
        const int row = ci >> 3;
        const int q   = (ci & 7) ^ (row & 7);
        goff[s] = row * D_DIM + q * 16;
    }

    // A fragment LDS byte offsets: for ks, frag row r: chunk q = ks*2+(quad>>1),
    // slot = r*8 + (q ^ (r&7)), + (quad&1)*8
    int slotA[4][4];   // [ks][it]
    #pragma unroll
    for (int ks = 0; ks < 4; ++ks) {
        const int q = ks * 2 + (quad >> 1);
        #pragma unroll
        for (int f = 0; f < 4; ++f) {
            const int r = f * 16 + c;
            slotA[ks][f] = (r * 8 + (q ^ (r & 7))) * 16 + (quad & 1) * 8;
        }
    }

    // B fragment global byte offsets (per lane): [ks][jt]
    int boff[4][4];
    #pragma unroll
    for (int ks = 0; ks < 4; ++ks)
        #pragma unroll
        for (int jt = 0; jt < 4; ++jt)
            boff[ks][jt] = (jt * 16 + c) * D_DIM
                         + (ks * 2 + (quad >> 1)) * 16 + (quad & 1) * 8;

    floatx4 acc[4][4] = {};
    long breg[2][4][4];   // reg-dbuf; all indices compile-time (full unroll)

    // prologue: tile0 (A0 lds + B0 reg) then tile1 — oldest-24 = tile0.
    #pragma unroll
    for (int s = 0; s < 8; ++s)
        load16_to_lds(Ag + goff[s], As[0] + (s * 64 + lane) * 16);
    #pragma unroll
    for (int ks = 0; ks < 4; ++ks)
        #pragma unroll
        for (int jt = 0; jt < 4; ++jt)
            breg[0][ks][jt] = *(const long*)(Bg + boff[ks][jt]);
    #pragma unroll
    for (int s = 0; s < 8; ++s)
        load16_to_lds(Ag + goff[s] + 128, As[1] + (s * 64 + lane) * 16);
    #pragma unroll
    for (int ks = 0; ks < 4; ++ks)
        #pragma unroll
        for (int jt = 0; jt < 4; ++jt)
            breg[1][ks][jt] = *(const long*)(Bg + boff[ks][jt] + 128);
    __builtin_amdgcn_sched_barrier(0);   // pin prologue issues

    #pragma unroll
    for (int kt = 0; kt < 6; ++kt) {
        // tile kt's 24 loads are the oldest in the queue
        if (kt <= 4) __builtin_amdgcn_s_waitcnt(WAIT_VM24);
        else         __builtin_amdgcn_s_waitcnt(WAIT_VM0);
        __builtin_amdgcn_sched_barrier(0);   // no ds_read hoists above the wait

        const unsigned char* Ab = As[kt & 1];

        __builtin_amdgcn_s_setprio(1);
        #pragma unroll
        for (int ks = 0; ks < 4; ++ks) {
            long af[4];
            #pragma unroll
            for (int it = 0; it < 4; ++it)
                af[it] = *(const long*)(Ab + slotA[ks][it]);

            #pragma unroll
            for (int it = 0; it < 4; ++it)
                #pragma unroll
                for (int jt = 0; jt < 4; ++jt)
                    acc[it][jt] = __builtin_amdgcn_mfma_f32_16x16x32_fp8_fp8(
                        af[it], breg[kt & 1][ks][jt], acc[it][jt], 0, 0, 0);
        }
        __builtin_amdgcn_s_setprio(0);

        if (kt < 4) {
            const int k0 = (kt + 2) * 128;
            __builtin_amdgcn_s_waitcnt(WAIT_LGKM0);   // As[kt&1] reads retired
            #pragma unroll
            for (int s = 0; s < 8; ++s)
                load16_to_lds(Ag + goff[s] + k0, As[kt & 1] + (s * 64 + lane) * 16);
            #pragma unroll
            for (int ks = 0; ks < 4; ++ks)
                #pragma unroll
                for (int jt = 0; jt < 4; ++jt)
                    breg[kt & 1][ks][jt] = *(const long*)(Bg + boff[ks][jt] + k0);
            __builtin_amdgcn_sched_barrier(0);   // pin issues before next wait
        }
    }

    const float w = wp[0];

    // per-column fixed-offset partial: sum exp(w*(cos-1)) over the 64 rows
    #pragma unroll
    for (int jt = 0; jt < 4; ++jt) {
        float sm = 0.f;
        #pragma unroll
        for (int it = 0; it < 4; ++it)
            #pragma unroll
            for (int r = 0; r < 4; ++r)
                sm += __expf(w * (acc[it][jt][r] - 1.0f));
        sm += __shfl_xor(sm, 16);
        sm += __shfl_xor(sm, 32);
        if (quad == 0) Psum[(size_t)bu * N_SPK + j0 + jt * 16 + c] = sm;
    }

    // target sims: row within m-slab == (m*1024+col)/20 (unique owner -> store)
    #pragma unroll
    for (int it = 0; it < 4; ++it) {
        #pragma unroll
        for (int jt = 0; jt < 4; ++jt) {
            const int col = j0 + jt * 16 + c;
            const int g = m * N_SPK + col;
            const int istar = g / M_UTT;
            const int rloc = rb * 64 + it * 16 + quad * 4;
            #pragma unroll
            for (int r = 0; r < 4; ++r) {
                if (rloc + r == istar) T[g] = acc[it][jt][r];
            }
        }
    }
}

// ---------------------------------------------------------------------------
// Kernel 3: combine 16 row-block partials per (m,j) -> loss term; block sum;
// last-block writes output (ctr/accum zeroed by prep).
// term = (w*T+b) - ((w+b) + log S) = w*(T-1) - log S.
// ---------------------------------------------------------------------------
__global__ void combine_kernel(const float* __restrict__ Psum,
                               const float* __restrict__ T,
                               const float* __restrict__ wp,
                               int* __restrict__ ctr,
                               float* __restrict__ accum,
                               float* __restrict__ out) {
    const int p = blockIdx.x * 256 + threadIdx.x;
    const int m = p >> 10;
    const int j = p & 1023;
    const float w = wp[0];

    float S = 0.f;
    #pragma unroll
    for (int rb = 0; rb < 16; ++rb)
        S += Psum[(size_t)(m * 16 + rb) * N_SPK + j];
    const float term = w * (T[p] - 1.0f) - __logf(S);

    __shared__ float red[256];
    red[threadIdx.x] = term;
    __syncthreads();
    for (int o = 128; o > 0; o >>= 1) {
        if (threadIdx.x < o) red[threadIdx.x] += red[threadIdx.x + o];
        __syncthreads();
    }
    if (threadIdx.x == 0) {
        atomicAdd(accum, red[0]);
        __threadfence();
        const int old = atomicAdd(ctr, 1);
        if (old == 79) {
            const float a = atomicAdd(accum, 0.0f);   // coherent read
            out[0] = -a / (float)NM_ROWS;
        }
    }
}

// ---------------------------------------------------------------------------
extern "C" void kernel_launch(void* const* d_in, const int* in_sizes, int n_in,
                              void* d_out, int out_size, void* d_ws, size_t ws_size,
                              hipStream_t stream) {
    const float* emb = (const float*)d_in[0];
    const float* wp  = (const float*)d_in[1];
    float* out = (float*)d_out;

    char* ws = (char*)d_ws;
    //   Ehat fp8 [M][N][D] : 15,728,640  @ 0
    //   Chat fp8 [N][D]    :    786,432  @ 15,728,640
    //   Psum f32 [320][N]  :  1,310,720  @ 16,515,072
    //   T    f32 [M][N]    :     81,920  @ 17,825,792
    //   ctr i32 + accum f32:          8  @ 17,907,712
    unsigned char* ehat = (unsigned char*)(ws);
    unsigned char* chat = (unsigned char*)(ws + 15728640);
    float* Psum  = (float*)(ws + 16515072);
    float* T     = (float*)(ws + 17825792);
    int*   ctr   = (int*)  (ws + 17907712);
    float* accum = (float*)(ws + 17907716);

    prep_kernel<<<dim3(N_SPK), dim3(384), 0, stream>>>(emb, ehat, chat, ctr, accum);
    gemm_fused_kernel<<<dim3(5120), dim3(64), 0, stream>>>(ehat, chat, wp, Psum, T);
    combine_kernel<<<dim3(80), dim3(256), 0, stream>>>(Psum, T, wp, ctr, accum, out);
}

// Round 4
// 157.785 us; speedup vs baseline: 1.0821x; 1.0821x over previous
//
#include <hip/hip_runtime.h>
#include <hip/hip_bf16.h>
#include <cstdint>

#define N_SPK 1024
#define M_UTT 20
#define D_DIM 768
#define NM_ROWS (N_SPK * M_UTT)   // 20480 utterances / rows

static constexpr float EPS = 1e-8f;

typedef __attribute__((ext_vector_type(4))) float floatx4;  // MFMA accumulator

__device__ __forceinline__ void load16_to_lds(const void* g, void* l) {
    __builtin_amdgcn_global_load_lds(
        (const __attribute__((address_space(1))) uint32_t*)g,
        (__attribute__((address_space(3))) uint32_t*)l, 16, 0, 0);
}

__device__ __forceinline__ float wave_sum(float v) {
    #pragma unroll
    for (int o = 32; o > 0; o >>= 1) v += __shfl_xor(v, o);
    return v;
}

// pack two f32 -> two OCP e4m3 bytes (low word of result)
__device__ __forceinline__ unsigned short fp8pk(float a, float b) {
    return (unsigned short)(__builtin_amdgcn_cvt_pk_fp8_f32(a, b, 0, false) & 0xFFFF);
}

// ---------------------------------------------------------------------------
// Kernel 1 (prep): per speaker, read emb once (float2/thread, 384 thr),
// centroid + 20 utterance norms; write FP8 e4m3 Ehat ([m][i][d]) and Chat.
// Zero-inits ctr/accum.  (unchanged — isolate the gemm change)
// ---------------------------------------------------------------------------
__global__ __launch_bounds__(384) void prep_kernel(const float* __restrict__ emb,
                                                   unsigned char* __restrict__ ehat,
                                                   unsigned char* __restrict__ chat,
                                                   int* __restrict__ ctr,
                                                   float* __restrict__ accum) {
    const int i = blockIdx.x;      // speaker
    const int t = threadIdx.x;     // 0..383
    const int wave = t >> 6, lane = t & 63;

    if (i == 0 && t == 0) { *ctr = 0; *accum = 0.f; }

    const float2* src = (const float2*)(emb + (size_t)i * M_UTT * D_DIM);

    float2 v[M_UTT];
    float ss[M_UTT];
    float2 cen = {0.f, 0.f};
    #pragma unroll
    for (int m = 0; m < M_UTT; ++m) {
        const float2 x = src[m * 384 + t];
        v[m] = x;
        ss[m] = x.x * x.x + x.y * x.y;
        cen.x += x.x; cen.y += x.y;
    }
    cen.x *= (1.f / M_UTT); cen.y *= (1.f / M_UTT);
    float css = cen.x * cen.x + cen.y * cen.y;

    __shared__ float red[M_UTT + 1][6];
    #pragma unroll
    for (int m = 0; m < M_UTT; ++m) {
        const float s = wave_sum(ss[m]);
        if (lane == 0) red[m][wave] = s;
    }
    {
        const float s = wave_sum(css);
        if (lane == 0) red[M_UTT][wave] = s;
    }
    __syncthreads();

    #pragma unroll
    for (int m = 0; m < M_UTT; ++m) {
        const float tot = red[m][0] + red[m][1] + red[m][2] +
                          red[m][3] + red[m][4] + red[m][5];
        const float rn = 1.0f / fmaxf(sqrtf(tot), EPS);
        ((unsigned short*)(ehat + ((size_t)(m * N_SPK + i)) * D_DIM))[t] =
            fp8pk(v[m].x * rn, v[m].y * rn);
    }
    {
        const float tot = red[M_UTT][0] + red[M_UTT][1] + red[M_UTT][2] +
                          red[M_UTT][3] + red[M_UTT][4] + red[M_UTT][5];
        const float rn = 1.0f / fmaxf(sqrtf(tot), EPS);
        ((unsigned short*)(chat + (size_t)i * D_DIM))[t] =
            fp8pk(cen.x * rn, cen.y * rn);
    }
}

// ---------------------------------------------------------------------------
// Kernel 2 (REWRITTEN): 128x128 tile, 4 waves (2x2 quadrants of 64x64),
// BK=64, 12 K-iters, m97-style 2-barrier double-buffer.
//   - LDS: 2 x (8KB A + 8KB B) = 32 KB -> 5 blocks/CU = 20 waves/CU, and
//     1280 blocks = 5 x 256 CU exactly (single generation, no tail).
//   - Staged L2 traffic halves vs 64x64 tiles: 491 -> 252 MB.
//   - Schedule per iter: issue stage(kt+1) -> compute(kt) -> barrier
//     (loads hide under a full compute phase; per-CU MFMA demand ~3100 cy/iter
//      now exceeds per-CU staging ~2000 cy/iter -> compute-dominated).
//   - LDS layout per operand tile [128 rows][64 B], 16B chunks XOR-swizzled:
//     lds_chunk = q ^ ((row>>1)&3). Staging pre-swizzles the GLOBAL source
//     per lane (dest stays linear, as global_load_lds requires); reads apply
//     the same XOR -> involution consistent. ~4-way b64 conflicts (like R0).
// Numerics bitwise-identical to R0 path: same ehat/chat bytes, same MFMA
// shape, same K-slice accumulation order.
// ---------------------------------------------------------------------------
__global__ __launch_bounds__(256, 5) void gemm_fused_kernel(
        const unsigned char* __restrict__ ehat,
        const unsigned char* __restrict__ chat,
        const float* __restrict__ wp,
        float* __restrict__ Psum,
        float* __restrict__ T) {
    __shared__ unsigned char As[2][128 * 64];   // 2 x 8 KB
    __shared__ unsigned char Bs[2][128 * 64];   // 2 x 8 KB

    const int t    = threadIdx.x;
    const int lane = t & 63;
    const int wid  = t >> 6;        // 0..3
    const int c    = lane & 15;
    const int quad = lane >> 4;
    const int wr   = wid >> 1;      // row quadrant 0..1
    const int wc   = wid & 1;       // col quadrant 0..1

    const int xcd = blockIdx.x & 7;
    const int idx = blockIdx.x >> 3;        // 0..159 per XCD
    const int bu  = xcd * 20 + (idx >> 3);  // 0..159 (128-row tiles)
    const int bj  = idx & 7;                // 0..7   (bj fastest within XCD)
    const int m   = bu >> 3;                // 8 bu-tiles per m
    const int rb8 = bu & 7;
    const int u0  = bu * 128;
    const int j0  = bj * 128;

    const unsigned char* Ag = ehat + (size_t)u0 * D_DIM;
    const unsigned char* Bg = chat + (size_t)j0 * D_DIM;

    // staging: 512 16B chunks per operand tile; this wave covers
    // ci = s*256 + wid*64 + lane for s=0,1. Dest is LINEAR at ci*16;
    // the global source chunk is pre-swizzled: qg = (ci&3) ^ ((row>>1)&3).
    int goff[2];
    #pragma unroll
    for (int s = 0; s < 2; ++s) {
        const int ci  = s * 256 + wid * 64 + lane;
        const int row = ci >> 2;                    // 0..127
        const int qg  = (ci & 3) ^ ((row >> 1) & 3);
        goff[s] = row * D_DIM + qg * 16;
    }

    // fragment LDS byte offsets (A: quadrant rows wr*64.., B: cols wc*64..):
    // logical chunk q = ks*2 + (quad>>1); stored at q ^ ((r>>1)&3).
    int slotA[2][4], slotB[2][4];   // [ks][frag]
    #pragma unroll
    for (int ks = 0; ks < 2; ++ks) {
        const int q = ks * 2 + (quad >> 1);
        #pragma unroll
        for (int f = 0; f < 4; ++f) {
            const int rA = wr * 64 + f * 16 + c;
            const int rB = wc * 64 + f * 16 + c;
            slotA[ks][f] = rA * 64 + ((q ^ ((rA >> 1) & 3)) * 16) + (quad & 1) * 8;
            slotB[ks][f] = rB * 64 + ((q ^ ((rB >> 1) & 3)) * 16) + (quad & 1) * 8;
        }
    }

    floatx4 acc[4][4] = {};

    // prologue: stage K-tile 0 into buf 0
    #pragma unroll
    for (int s = 0; s < 2; ++s) {
        load16_to_lds(Ag + goff[s], &As[0][(s * 256 + wid * 64 + lane) * 16]);
        load16_to_lds(Bg + goff[s], &Bs[0][(s * 256 + wid * 64 + lane) * 16]);
    }
    __syncthreads();   // compiler emits vmcnt(0) drain before s_barrier

    #pragma unroll
    for (int kt = 0; kt < 12; ++kt) {
        const int cur = kt & 1;
        const int nxt = cur ^ 1;

        if (kt < 11) {
            const int k0 = (kt + 1) * 64;
            #pragma unroll
            for (int s = 0; s < 2; ++s) {
                load16_to_lds(Ag + goff[s] + k0,
                              &As[nxt][(s * 256 + wid * 64 + lane) * 16]);
                load16_to_lds(Bg + goff[s] + k0,
                              &Bs[nxt][(s * 256 + wid * 64 + lane) * 16]);
            }
        }

        #pragma unroll
        for (int ks = 0; ks < 2; ++ks) {
            long af[4], bf[4];
            #pragma unroll
            for (int f = 0; f < 4; ++f)
                af[f] = *(const long*)(&As[cur][slotA[ks][f]]);
            #pragma unroll
            for (int f = 0; f < 4; ++f)
                bf[f] = *(const long*)(&Bs[cur][slotB[ks][f]]);

            #pragma unroll
            for (int it = 0; it < 4; ++it)
                #pragma unroll
                for (int jt = 0; jt < 4; ++jt)
                    acc[it][jt] = __builtin_amdgcn_mfma_f32_16x16x32_fp8_fp8(
                        af[it], bf[jt], acc[it][jt], 0, 0, 0);
        }

        if (kt < 11) __syncthreads();   // drains vmcnt (next tile landed) + sync
    }

    const float w = wp[0];
    const int rb320 = bu * 2 + wr;      // 64-row block index, 0..319

    // per-column fixed-offset partial: sum exp(w*(cos-1)) over quadrant's 64 rows
    #pragma unroll
    for (int jt = 0; jt < 4; ++jt) {
        float sm = 0.f;
        #pragma unroll
        for (int it = 0; it < 4; ++it)
            #pragma unroll
            for (int r = 0; r < 4; ++r)
                sm += __expf(w * (acc[it][jt][r] - 1.0f));
        sm += __shfl_xor(sm, 16);
        sm += __shfl_xor(sm, 32);
        if (quad == 0)
            Psum[(size_t)rb320 * N_SPK + j0 + wc * 64 + jt * 16 + c] = sm;
    }

    // target sims: local row within m-slab == (m*1024+col)/20 (unique owner)
    #pragma unroll
    for (int it = 0; it < 4; ++it) {
        #pragma unroll
        for (int jt = 0; jt < 4; ++jt) {
            const int col = j0 + wc * 64 + jt * 16 + c;
            const int g = m * N_SPK + col;
            const int istar = g / M_UTT;
            const int rloc = rb8 * 128 + wr * 64 + it * 16 + quad * 4;
            #pragma unroll
            for (int r = 0; r < 4; ++r) {
                if (rloc + r == istar) T[g] = acc[it][jt][r];
            }
        }
    }
}

// ---------------------------------------------------------------------------
// Kernel 3: combine 16 row-block partials per (m,j) -> loss term; block sum;
// last-block writes output (ctr/accum zeroed by prep).
// term = (w*T+b) - ((w+b) + log S) = w*(T-1) - log S.
// ---------------------------------------------------------------------------
__global__ void combine_kernel(const float* __restrict__ Psum,
                               const float* __restrict__ T,
                               const float* __restrict__ wp,
                               int* __restrict__ ctr,
                               float* __restrict__ accum,
                               float* __restrict__ out) {
    const int p = blockIdx.x * 256 + threadIdx.x;
    const int m = p >> 10;
    const int j = p & 1023;
    const float w = wp[0];

    float S = 0.f;
    #pragma unroll
    for (int rb = 0; rb < 16; ++rb)
        S += Psum[(size_t)(m * 16 + rb) * N_SPK + j];
    const float term = w * (T[p] - 1.0f) - __logf(S);

    __shared__ float red[256];
    red[threadIdx.x] = term;
    __syncthreads();
    for (int o = 128; o > 0; o >>= 1) {
        if (threadIdx.x < o) red[threadIdx.x] += red[threadIdx.x + o];
        __syncthreads();
    }
    if (threadIdx.x == 0) {
        atomicAdd(accum, red[0]);
        __threadfence();
        const int old = atomicAdd(ctr, 1);
        if (old == 79) {
            const float a = atomicAdd(accum, 0.0f);   // coherent read
            out[0] = -a / (float)NM_ROWS;
        }
    }
}

// ---------------------------------------------------------------------------
extern "C" void kernel_launch(void* const* d_in, const int* in_sizes, int n_in,
                              void* d_out, int out_size, void* d_ws, size_t ws_size,
                              hipStream_t stream) {
    const float* emb = (const float*)d_in[0];
    const float* wp  = (const float*)d_in[1];
    float* out = (float*)d_out;

    char* ws = (char*)d_ws;
    //   Ehat fp8 [M][N][D] : 15,728,640  @ 0
    //   Chat fp8 [N][D]    :    786,432  @ 15,728,640
    //   Psum f32 [320][N]  :  1,310,720  @ 16,515,072
    //   T    f32 [M][N]    :     81,920  @ 17,825,792
    //   ctr i32 + accum f32:          8  @ 17,907,712
    unsigned char* ehat = (unsigned char*)(ws);
    unsigned char* chat = (unsigned char*)(ws + 15728640);
    float* Psum  = (float*)(ws + 16515072);
    float* T     = (float*)(ws + 17825792);
    int*   ctr   = (int*)  (ws + 17907712);
    float* accum = (float*)(ws + 17907716);

    prep_kernel<<<dim3(N_SPK), dim3(384), 0, stream>>>(emb, ehat, chat, ctr, accum);
    gemm_fused_kernel<<<dim3(1280), dim3(256), 0, stream>>>(ehat, chat, wp, Psum, T);
    combine_kernel<<<dim3(80), dim3(256), 0, stream>>>(Psum, T, wp, ctr, accum, out);
}

// Round 5
// 131.663 us; speedup vs baseline: 1.2968x; 1.1984x over previous
//
#include <hip/hip_runtime.h>
#include <hip/hip_bf16.h>
#include <cstdint>

#define N_SPK 1024
#define M_UTT 20
#define D_DIM 768
#define NM_ROWS (N_SPK * M_UTT)   // 20480 utterances / rows

static constexpr float EPS = 1e-8f;

typedef __attribute__((ext_vector_type(4))) float floatx4;  // MFMA accumulator
typedef __attribute__((ext_vector_type(2))) long longx2;    // ds_read_b128 pair

__device__ __forceinline__ void load16_to_lds(const void* g, void* l) {
    __builtin_amdgcn_global_load_lds(
        (const __attribute__((address_space(1))) uint32_t*)g,
        (__attribute__((address_space(3))) uint32_t*)l, 16, 0, 0);
}

__device__ __forceinline__ float wave_sum(float v) {
    #pragma unroll
    for (int o = 32; o > 0; o >>= 1) v += __shfl_xor(v, o);
    return v;
}

// pack two f32 -> two OCP e4m3 bytes (low word of result)
__device__ __forceinline__ unsigned short fp8pk(float a, float b) {
    return (unsigned short)(__builtin_amdgcn_cvt_pk_fp8_f32(a, b, 0, false) & 0xFFFF);
}

// K-interleave permutation, applied at PREP time within each 64-byte K-block:
//   orig byte d = h*32 + q*8 + b  ->  stored byte dp = q*16 + h*8 + b
// so a lane's (ks0,ks1) 8B fragments become one contiguous 16B chunk (chunk q).
__device__ __forceinline__ int kperm(int d) {
    return (d & ~63) | (((d >> 3) & 3) << 4) | (((d >> 5) & 1) << 3) | (d & 7);
}

// ---------------------------------------------------------------------------
// Kernel 1 (prep): per speaker, read emb once (float2/thread, 384 thr),
// centroid + 20 utterance norms; write FP8 e4m3 Ehat ([m][i][dp]) and Chat
// in the K-interleaved layout (kperm). Zero-inits ctr/accum.
// ---------------------------------------------------------------------------
__global__ __launch_bounds__(384) void prep_kernel(const float* __restrict__ emb,
                                                   unsigned char* __restrict__ ehat,
                                                   unsigned char* __restrict__ chat,
                                                   int* __restrict__ ctr,
                                                   float* __restrict__ accum) {
    const int i = blockIdx.x;      // speaker
    const int t = threadIdx.x;     // 0..383
    const int wave = t >> 6, lane = t & 63;

    if (i == 0 && t == 0) { *ctr = 0; *accum = 0.f; }

    const float2* src = (const float2*)(emb + (size_t)i * M_UTT * D_DIM);
    const int dp = kperm(t * 2);   // byte index of the fp8 pair in stored layout

    float2 v[M_UTT];
    float ss[M_UTT];
    float2 cen = {0.f, 0.f};
    #pragma unroll
    for (int m = 0; m < M_UTT; ++m) {
        const float2 x = src[m * 384 + t];
        v[m] = x;
        ss[m] = x.x * x.x + x.y * x.y;
        cen.x += x.x; cen.y += x.y;
    }
    cen.x *= (1.f / M_UTT); cen.y *= (1.f / M_UTT);
    float css = cen.x * cen.x + cen.y * cen.y;

    __shared__ float red[M_UTT + 1][6];
    #pragma unroll
    for (int m = 0; m < M_UTT; ++m) {
        const float s = wave_sum(ss[m]);
        if (lane == 0) red[m][wave] = s;
    }
    {
        const float s = wave_sum(css);
        if (lane == 0) red[M_UTT][wave] = s;
    }
    __syncthreads();

    #pragma unroll
    for (int m = 0; m < M_UTT; ++m) {
        const float tot = red[m][0] + red[m][1] + red[m][2] +
                          red[m][3] + red[m][4] + red[m][5];
        const float rn = 1.0f / fmaxf(sqrtf(tot), EPS);
        *(unsigned short*)(ehat + ((size_t)(m * N_SPK + i)) * D_DIM + dp) =
            fp8pk(v[m].x * rn, v[m].y * rn);
    }
    {
        const float tot = red[M_UTT][0] + red[M_UTT][1] + red[M_UTT][2] +
                          red[M_UTT][3] + red[M_UTT][4] + red[M_UTT][5];
        const float rn = 1.0f / fmaxf(sqrtf(tot), EPS);
        *(unsigned short*)(chat + (size_t)i * D_DIM + dp) =
            fp8pk(cen.x * rn, cen.y * rn);
    }
}

// ---------------------------------------------------------------------------
// Kernel 2: 128x128 tile, 4 waves (2x2 quadrants of 64x64), BK=64, 12 K-iters,
// 2-barrier double-buffer.
//   R5 fixes vs R4:
//   - __launch_bounds__(256, 4): 128-reg budget (was 5 -> 102-reg cap ->
//     ~70 MB/dispatch scratch spill traffic, the R4 regression).
//   - K-interleaved operand layout (kperm, done in prep) + XOR chunk swizzle:
//     each lane's per-f fragment pair is ONE ds_read_b128, and for each f the
//     64 lanes read every 16B slot of a contiguous 1KB region exactly once ->
//     zero bank conflicts, 8 (not 16) LDS reads per K-iter.
//     Fragment bytes are bitwise-identical to the R0 path (derivation in
//     kperm comment), so numerics are unchanged.
// ---------------------------------------------------------------------------
__global__ __launch_bounds__(256, 4) void gemm_fused_kernel(
        const unsigned char* __restrict__ ehat,
        const unsigned char* __restrict__ chat,
        const float* __restrict__ wp,
        float* __restrict__ Psum,
        float* __restrict__ T) {
    __shared__ unsigned char As[2][128 * 64];   // 2 x 8 KB
    __shared__ unsigned char Bs[2][128 * 64];   // 2 x 8 KB

    const int t    = threadIdx.x;
    const int lane = t & 63;
    const int wid  = t >> 6;        // 0..3
    const int c    = lane & 15;
    const int quad = lane >> 4;
    const int wr   = wid >> 1;      // row quadrant 0..1
    const int wc   = wid & 1;       // col quadrant 0..1

    const int xcd = blockIdx.x & 7;
    const int idx = blockIdx.x >> 3;        // 0..159 per XCD
    const int bu  = xcd * 20 + (idx >> 3);  // 0..159 (128-row tiles)
    const int bj  = idx & 7;                // 0..7   (bj fastest within XCD)
    const int m   = bu >> 3;                // 8 bu-tiles per m
    const int rb8 = bu & 7;
    const int u0  = bu * 128;
    const int j0  = bj * 128;

    const unsigned char* Ag = ehat + (size_t)u0 * D_DIM;
    const unsigned char* Bg = chat + (size_t)j0 * D_DIM;

    // staging: 512 16B chunks per operand tile; this wave covers
    // ci = s*256 + wid*64 + lane for s=0,1. Dest is LINEAR at ci*16; the
    // global source chunk is pre-swizzled: stored[p] gets L-chunk p^swz(row).
    int goff[2];
    #pragma unroll
    for (int s = 0; s < 2; ++s) {
        const int ci  = s * 256 + wid * 64 + lane;
        const int row = ci >> 2;                    // 0..127
        const int qg  = (ci & 3) ^ ((row >> 1) & 3);
        goff[s] = row * D_DIM + qg * 16;
    }

    // fragment read: lane wants L-chunk 'quad' of its row -> stored position
    // quad ^ swz(row). One b128 per f delivers {ks0, ks1} fragments.
    int slotA[4], slotB[4];   // [frag]
    #pragma unroll
    for (int f = 0; f < 4; ++f) {
        const int rA = wr * 64 + f * 16 + c;
        const int rB = wc * 64 + f * 16 + c;
        slotA[f] = rA * 64 + ((quad ^ ((rA >> 1) & 3)) * 16);
        slotB[f] = rB * 64 + ((quad ^ ((rB >> 1) & 3)) * 16);
    }

    floatx4 acc[4][4] = {};

    // prologue: stage K-tile 0 into buf 0
    #pragma unroll
    for (int s = 0; s < 2; ++s) {
        load16_to_lds(Ag + goff[s], &As[0][(s * 256 + wid * 64 + lane) * 16]);
        load16_to_lds(Bg + goff[s], &Bs[0][(s * 256 + wid * 64 + lane) * 16]);
    }
    __syncthreads();   // compiler emits vmcnt(0) drain before s_barrier

    #pragma unroll
    for (int kt = 0; kt < 12; ++kt) {
        const int cur = kt & 1;
        const int nxt = cur ^ 1;

        if (kt < 11) {
            const int k0 = (kt + 1) * 64;
            #pragma unroll
            for (int s = 0; s < 2; ++s) {
                load16_to_lds(Ag + goff[s] + k0,
                              &As[nxt][(s * 256 + wid * 64 + lane) * 16]);
                load16_to_lds(Bg + goff[s] + k0,
                              &Bs[nxt][(s * 256 + wid * 64 + lane) * 16]);
            }
        }

        longx2 af[4], bf[4];
        #pragma unroll
        for (int f = 0; f < 4; ++f)
            af[f] = *(const longx2*)(&As[cur][slotA[f]]);
        #pragma unroll
        for (int f = 0; f < 4; ++f)
            bf[f] = *(const longx2*)(&Bs[cur][slotB[f]]);

        #pragma unroll
        for (int ks = 0; ks < 2; ++ks)
            #pragma unroll
            for (int it = 0; it < 4; ++it)
                #pragma unroll
                for (int jt = 0; jt < 4; ++jt)
                    acc[it][jt] = __builtin_amdgcn_mfma_f32_16x16x32_fp8_fp8(
                        af[it][ks], bf[jt][ks], acc[it][jt], 0, 0, 0);

        if (kt < 11) __syncthreads();   // drains vmcnt (next tile landed) + sync
    }

    const float w = wp[0];
    const int rb320 = bu * 2 + wr;      // 64-row block index, 0..319

    // per-column fixed-offset partial: sum exp(w*(cos-1)) over quadrant's 64 rows
    #pragma unroll
    for (int jt = 0; jt < 4; ++jt) {
        float sm = 0.f;
        #pragma unroll
        for (int it = 0; it < 4; ++it)
            #pragma unroll
            for (int r = 0; r < 4; ++r)
                sm += __expf(w * (acc[it][jt][r] - 1.0f));
        sm += __shfl_xor(sm, 16);
        sm += __shfl_xor(sm, 32);
        if (quad == 0)
            Psum[(size_t)rb320 * N_SPK + j0 + wc * 64 + jt * 16 + c] = sm;
    }

    // target sims: local row within m-slab == (m*1024+col)/20 (unique owner)
    #pragma unroll
    for (int it = 0; it < 4; ++it) {
        #pragma unroll
        for (int jt = 0; jt < 4; ++jt) {
            const int col = j0 + wc * 64 + jt * 16 + c;
            const int g = m * N_SPK + col;
            const int istar = g / M_UTT;
            const int rloc = rb8 * 128 + wr * 64 + it * 16 + quad * 4;
            #pragma unroll
            for (int r = 0; r < 4; ++r) {
                if (rloc + r == istar) T[g] = acc[it][jt][r];
            }
        }
    }
}

// ---------------------------------------------------------------------------
// Kernel 3: combine 16 row-block partials per (m,j) -> loss term; block sum;
// last-block writes output (ctr/accum zeroed by prep).
// term = (w*T+b) - ((w+b) + log S) = w*(T-1) - log S.
// ---------------------------------------------------------------------------
__global__ void combine_kernel(const float* __restrict__ Psum,
                               const float* __restrict__ T,
                               const float* __restrict__ wp,
                               int* __restrict__ ctr,
                               float* __restrict__ accum,
                               float* __restrict__ out) {
    const int p = blockIdx.x * 256 + threadIdx.x;
    const int m = p >> 10;
    const int j = p & 1023;
    const float w = wp[0];

    float S = 0.f;
    #pragma unroll
    for (int rb = 0; rb < 16; ++rb)
        S += Psum[(size_t)(m * 16 + rb) * N_SPK + j];
    const float term = w * (T[p] - 1.0f) - __logf(S);

    __shared__ float red[256];
    red[threadIdx.x] = term;
    __syncthreads();
    for (int o = 128; o > 0; o >>= 1) {
        if (threadIdx.x < o) red[threadIdx.x] += red[threadIdx.x + o];
        __syncthreads();
    }
    if (threadIdx.x == 0) {
        atomicAdd(accum, red[0]);
        __threadfence();
        const int old = atomicAdd(ctr, 1);
        if (old == 79) {
            const float a = atomicAdd(accum, 0.0f);   // coherent read
            out[0] = -a / (float)NM_ROWS;
        }
    }
}

// ---------------------------------------------------------------------------
extern "C" void kernel_launch(void* const* d_in, const int* in_sizes, int n_in,
                              void* d_out, int out_size, void* d_ws, size_t ws_size,
                              hipStream_t stream) {
    const float* emb = (const float*)d_in[0];
    const float* wp  = (const float*)d_in[1];
    float* out = (float*)d_out;

    char* ws = (char*)d_ws;
    //   Ehat fp8 [M][N][D] : 15,728,640  @ 0
    //   Chat fp8 [N][D]    :    786,432  @ 15,728,640
    //   Psum f32 [320][N]  :  1,310,720  @ 16,515,072
    //   T    f32 [M][N]    :     81,920  @ 17,825,792
    //   ctr i32 + accum f32:          8  @ 17,907,712
    unsigned char* ehat = (unsigned char*)(ws);
    unsigned char* chat = (unsigned char*)(ws + 15728640);
    float* Psum  = (float*)(ws + 16515072);
    float* T     = (float*)(ws + 17825792);
    int*   ctr   = (int*)  (ws + 17907712);
    float* accum = (float*)(ws + 17907716);

    prep_kernel<<<dim3(N_SPK), dim3(384), 0, stream>>>(emb, ehat, chat, ctr, accum);
    gemm_fused_kernel<<<dim3(1280), dim3(256), 0, stream>>>(ehat, chat, wp, Psum, T);
    combine_kernel<<<dim3(80), dim3(256), 0, stream>>>(Psum, T, wp, ctr, accum, out);
}

// Round 6
// 129.609 us; speedup vs baseline: 1.3174x; 1.0158x over previous
//
#include <hip/hip_runtime.h>
#include <hip/hip_bf16.h>
#include <cstdint>

#define N_SPK 1024
#define M_UTT 20
#define D_DIM 768
#define NM_ROWS (N_SPK * M_UTT)   // 20480 utterances / rows

static constexpr float EPS = 1e-8f;

typedef __attribute__((ext_vector_type(4))) float floatx4;  // MFMA accumulator
typedef __attribute__((ext_vector_type(4))) int   intx4;    // 16B LDS read
typedef __attribute__((ext_vector_type(8))) int   intx8;    // 32B MFMA operand

__device__ __forceinline__ void load16_to_lds(const void* g, void* l) {
    __builtin_amdgcn_global_load_lds(
        (const __attribute__((address_space(1))) uint32_t*)g,
        (__attribute__((address_space(3))) uint32_t*)l, 16, 0, 0);
}

__device__ __forceinline__ float wave_sum(float v) {
    #pragma unroll
    for (int o = 32; o > 0; o >>= 1) v += __shfl_xor(v, o);
    return v;
}

// pack two f32 -> two OCP e4m3 bytes (low word of result)
__device__ __forceinline__ unsigned short fp8pk(float a, float b) {
    return (unsigned short)(__builtin_amdgcn_cvt_pk_fp8_f32(a, b, 0, false) & 0xFFFF);
}

// K-interleave permutation (prep-time, within each 64-byte K-block). Applied
// identically to ehat and chat; the gemm reads both operands through identical
// addressing, so this global k-bijection cancels in the MFMA dot product
// (validated empirically in R5: absmax 0.0).
__device__ __forceinline__ int kperm(int d) {
    return (d & ~63) | (((d >> 3) & 3) << 4) | (((d >> 5) & 1) << 3) | (d & 7);
}

// ---------------------------------------------------------------------------
// Kernel 1 (prep): per speaker, read emb once (float2/thread, 384 thr),
// centroid + 20 utterance norms; write FP8 e4m3 Ehat ([m][i][dp]) and Chat.
// Zero-inits ctr/accum.  (unchanged — isolate the gemm change)
// ---------------------------------------------------------------------------
__global__ __launch_bounds__(384) void prep_kernel(const float* __restrict__ emb,
                                                   unsigned char* __restrict__ ehat,
                                                   unsigned char* __restrict__ chat,
                                                   int* __restrict__ ctr,
                                                   float* __restrict__ accum) {
    const int i = blockIdx.x;      // speaker
    const int t = threadIdx.x;     // 0..383
    const int wave = t >> 6, lane = t & 63;

    if (i == 0 && t == 0) { *ctr = 0; *accum = 0.f; }

    const float2* src = (const float2*)(emb + (size_t)i * M_UTT * D_DIM);
    const int dp = kperm(t * 2);   // byte index of the fp8 pair in stored layout

    float2 v[M_UTT];
    float ss[M_UTT];
    float2 cen = {0.f, 0.f};
    #pragma unroll
    for (int m = 0; m < M_UTT; ++m) {
        const float2 x = src[m * 384 + t];
        v[m] = x;
        ss[m] = x.x * x.x + x.y * x.y;
        cen.x += x.x; cen.y += x.y;
    }
    cen.x *= (1.f / M_UTT); cen.y *= (1.f / M_UTT);
    float css = cen.x * cen.x + cen.y * cen.y;

    __shared__ float red[M_UTT + 1][6];
    #pragma unroll
    for (int m = 0; m < M_UTT; ++m) {
        const float s = wave_sum(ss[m]);
        if (lane == 0) red[m][wave] = s;
    }
    {
        const float s = wave_sum(css);
        if (lane == 0) red[M_UTT][wave] = s;
    }
    __syncthreads();

    #pragma unroll
    for (int m = 0; m < M_UTT; ++m) {
        const float tot = red[m][0] + red[m][1] + red[m][2] +
                          red[m][3] + red[m][4] + red[m][5];
        const float rn = 1.0f / fmaxf(sqrtf(tot), EPS);
        *(unsigned short*)(ehat + ((size_t)(m * N_SPK + i)) * D_DIM + dp) =
            fp8pk(v[m].x * rn, v[m].y * rn);
    }
    {
        const float tot = red[M_UTT][0] + red[M_UTT][1] + red[M_UTT][2] +
                          red[M_UTT][3] + red[M_UTT][4] + red[M_UTT][5];
        const float rn = 1.0f / fmaxf(sqrtf(tot), EPS);
        *(unsigned short*)(chat + (size_t)i * D_DIM + dp) =
            fp8pk(cen.x * rn, cen.y * rn);
    }
}

// ---------------------------------------------------------------------------
// Kernel 2: 128x128 tile, 4 waves (2x2 quadrants of 64x64), BK=128, 6 K-iters,
// 2-barrier double-buffer — now on the MX-scaled fp8 pipe (2x rate).
//   R6 changes vs R5:
//   - mfma_scale_f32_16x16x128_f8f6f4 with unit scales (e8m0 0x7F = 1.0),
//     fmt codes cbsz=blgp=0 (fp8 e4m3). K=128 per instruction -> 16 MFMA/iter
//     on the 4647 TF pipe (vs 32 on the 2047 TF pipe): MFMA floor 15.6->6.9us.
//   - Correctness by A/B symmetry: both operands staged+read through identical
//     addressing, so the hardware k-layout permutation cancels (same argument
//     kperm already validated in R5).
//   - LDS [128 rows][128 B] per tile, 8 chunks/row XOR-swizzled by row&7:
//     logical chunk l stored at phys l^(row&7). Each fragment b128 read has
//     exactly 8 lanes per chunk-column -> minimum-cycle, conflict-free; the
//     lane's second 16B is at addr^64. Staging pre-swizzles the global source.
//   - dbuf 2x(16+16) KB = 64 KB -> 2 blocks/CU; __launch_bounds__(256,2)
//     gives a 256-VGPR budget for the ~150-reg working set (no spills).
// ---------------------------------------------------------------------------
__global__ __launch_bounds__(256, 2) void gemm_fused_kernel(
        const unsigned char* __restrict__ ehat,
        const unsigned char* __restrict__ chat,
        const float* __restrict__ wp,
        float* __restrict__ Psum,
        float* __restrict__ T) {
    __shared__ unsigned char As[2][128 * 128];   // 2 x 16 KB
    __shared__ unsigned char Bs[2][128 * 128];   // 2 x 16 KB

    const int t    = threadIdx.x;
    const int lane = t & 63;
    const int wid  = t >> 6;        // 0..3
    const int c    = lane & 15;
    const int quad = lane >> 4;
    const int wr   = wid >> 1;      // row quadrant 0..1
    const int wc   = wid & 1;       // col quadrant 0..1

    const int xcd = blockIdx.x & 7;
    const int idx = blockIdx.x >> 3;        // 0..159 per XCD
    const int bu  = xcd * 20 + (idx >> 3);  // 0..159 (128-row tiles)
    const int bj  = idx & 7;                // 0..7   (bj fastest within XCD)
    const int m   = bu >> 3;                // 8 bu-tiles per m
    const int rb8 = bu & 7;
    const int u0  = bu * 128;
    const int j0  = bj * 128;

    const unsigned char* Ag = ehat + (size_t)u0 * D_DIM;
    const unsigned char* Bg = chat + (size_t)j0 * D_DIM;

    // staging: 1024 16B chunks per operand tile; ci = s*256 + t, s=0..3.
    // Dest LINEAR at ci*16 (wave-uniform base + lane*16 by construction);
    // global source chunk pre-swizzled: phys p=ci&7 holds logical l=p^(row&7).
    int goff[4];
    #pragma unroll
    for (int s = 0; s < 4; ++s) {
        const int ci  = s * 256 + t;
        const int row = ci >> 3;                    // 0..127
        const int l   = (ci & 7) ^ (row & 7);
        goff[s] = row * D_DIM + l * 16;
    }

    // fragment read: lane wants logical chunks {quad, quad+4} of its row.
    // phys0 = quad ^ (row&7) (row&7 == c&7); second half at addr ^ 64.
    int slotA[4], slotB[4];   // [frag]
    #pragma unroll
    for (int f = 0; f < 4; ++f) {
        const int rA = wr * 64 + f * 16 + c;
        const int rB = wc * 64 + f * 16 + c;
        slotA[f] = rA * 128 + ((quad ^ (c & 7)) * 16);
        slotB[f] = rB * 128 + ((quad ^ (c & 7)) * 16);
    }

    floatx4 acc[4][4] = {};

    // prologue: stage K-tile 0 into buf 0
    #pragma unroll
    for (int s = 0; s < 4; ++s) {
        load16_to_lds(Ag + goff[s], &As[0][(s * 256 + t) * 16]);
        load16_to_lds(Bg + goff[s], &Bs[0][(s * 256 + t) * 16]);
    }
    __syncthreads();   // compiler emits vmcnt(0) drain before s_barrier

    #pragma unroll
    for (int kt = 0; kt < 6; ++kt) {
        const int cur = kt & 1;
        const int nxt = cur ^ 1;

        if (kt < 5) {
            const int k0 = (kt + 1) * 128;
            #pragma unroll
            for (int s = 0; s < 4; ++s) {
                load16_to_lds(Ag + goff[s] + k0, &As[nxt][(s * 256 + t) * 16]);
                load16_to_lds(Bg + goff[s] + k0, &Bs[nxt][(s * 256 + t) * 16]);
            }
        }

        intx8 av[4], bv[4];
        #pragma unroll
        for (int f = 0; f < 4; ++f) {
            const intx4 lo = *(const intx4*)(&As[cur][slotA[f]]);
            const intx4 hi = *(const intx4*)(&As[cur][slotA[f] ^ 64]);
            av[f] = __builtin_shufflevector(lo, hi, 0, 1, 2, 3, 4, 5, 6, 7);
        }
        #pragma unroll
        for (int f = 0; f < 4; ++f) {
            const intx4 lo = *(const intx4*)(&Bs[cur][slotB[f]]);
            const intx4 hi = *(const intx4*)(&Bs[cur][slotB[f] ^ 64]);
            bv[f] = __builtin_shufflevector(lo, hi, 0, 1, 2, 3, 4, 5, 6, 7);
        }

        #pragma unroll
        for (int it = 0; it < 4; ++it)
            #pragma unroll
            for (int jt = 0; jt < 4; ++jt)
                acc[it][jt] = __builtin_amdgcn_mfma_scale_f32_16x16x128_f8f6f4(
                    av[it], bv[jt], acc[it][jt],
                    0, 0,                      // cbsz=fp8(e4m3), blgp=fp8(e4m3)
                    0, 0x7F7F7F7F,             // A scales: e8m0 1.0
                    0, 0x7F7F7F7F);            // B scales: e8m0 1.0

        if (kt < 5) __syncthreads();   // drains vmcnt (next tile landed) + sync
    }

    const float w = wp[0];
    const int rb320 = bu * 2 + wr;      // 64-row block index, 0..319

    // per-column fixed-offset partial: sum exp(w*(cos-1)) over quadrant's 64 rows
    #pragma unroll
    for (int jt = 0; jt < 4; ++jt) {
        float sm = 0.f;
        #pragma unroll
        for (int it = 0; it < 4; ++it)
            #pragma unroll
            for (int r = 0; r < 4; ++r)
                sm += __expf(w * (acc[it][jt][r] - 1.0f));
        sm += __shfl_xor(sm, 16);
        sm += __shfl_xor(sm, 32);
        if (quad == 0)
            Psum[(size_t)rb320 * N_SPK + j0 + wc * 64 + jt * 16 + c] = sm;
    }

    // target sims: local row within m-slab == (m*1024+col)/20 (unique owner)
    #pragma unroll
    for (int it = 0; it < 4; ++it) {
        #pragma unroll
        for (int jt = 0; jt < 4; ++jt) {
            const int col = j0 + wc * 64 + jt * 16 + c;
            const int g = m * N_SPK + col;
            const int istar = g / M_UTT;
            const int rloc = rb8 * 128 + wr * 64 + it * 16 + quad * 4;
            #pragma unroll
            for (int r = 0; r < 4; ++r) {
                if (rloc + r == istar) T[g] = acc[it][jt][r];
            }
        }
    }
}

// ---------------------------------------------------------------------------
// Kernel 3: combine 16 row-block partials per (m,j) -> loss term; block sum;
// last-block writes output (ctr/accum zeroed by prep).
// term = (w*T+b) - ((w+b) + log S) = w*(T-1) - log S.
// ---------------------------------------------------------------------------
__global__ void combine_kernel(const float* __restrict__ Psum,
                               const float* __restrict__ T,
                               const float* __restrict__ wp,
                               int* __restrict__ ctr,
                               float* __restrict__ accum,
                               float* __restrict__ out) {
    const int p = blockIdx.x * 256 + threadIdx.x;
    const int m = p >> 10;
    const int j = p & 1023;
    const float w = wp[0];

    float S = 0.f;
    #pragma unroll
    for (int rb = 0; rb < 16; ++rb)
        S += Psum[(size_t)(m * 16 + rb) * N_SPK + j];
    const float term = w * (T[p] - 1.0f) - __logf(S);

    __shared__ float red[256];
    red[threadIdx.x] = term;
    __syncthreads();
    for (int o = 128; o > 0; o >>= 1) {
        if (threadIdx.x < o) red[threadIdx.x] += red[threadIdx.x + o];
        __syncthreads();
    }
    if (threadIdx.x == 0) {
        atomicAdd(accum, red[0]);
        __threadfence();
        const int old = atomicAdd(ctr, 1);
        if (old == 79) {
            const float a = atomicAdd(accum, 0.0f);   // coherent read
            out[0] = -a / (float)NM_ROWS;
        }
    }
}

// ---------------------------------------------------------------------------
extern "C" void kernel_launch(void* const* d_in, const int* in_sizes, int n_in,
                              void* d_out, int out_size, void* d_ws, size_t ws_size,
                              hipStream_t stream) {
    const float* emb = (const float*)d_in[0];
    const float* wp  = (const float*)d_in[1];
    float* out = (float*)d_out;

    char* ws = (char*)d_ws;
    //   Ehat fp8 [M][N][D] : 15,728,640  @ 0
    //   Chat fp8 [N][D]    :    786,432  @ 15,728,640
    //   Psum f32 [320][N]  :  1,310,720  @ 16,515,072
    //   T    f32 [M][N]    :     81,920  @ 17,825,792
    //   ctr i32 + accum f32:          8  @ 17,907,712
    unsigned char* ehat = (unsigned char*)(ws);
    unsigned char* chat = (unsigned char*)(ws + 15728640);
    float* Psum  = (float*)(ws + 16515072);
    float* T     = (float*)(ws + 17825792);
    int*   ctr   = (int*)  (ws + 17907712);
    float* accum = (float*)(ws + 17907716);

    prep_kernel<<<dim3(N_SPK), dim3(384), 0, stream>>>(emb, ehat, chat, ctr, accum);
    gemm_fused_kernel<<<dim3(1280), dim3(256), 0, stream>>>(ehat, chat, wp, Psum, T);
    combine_kernel<<<dim3(80), dim3(256), 0, stream>>>(Psum, T, wp, ctr, accum, out);
}